// Round 13
// baseline (265.550 us; speedup 1.0000x reference)
//
#include <hip/hip_runtime.h>
#include <hip/hip_bf16.h>

#define N_NODES 50000
#define N_EDGES 800000
#define H 128
#define IN_DIM 512
#define N_LAYERS 3
#define LN_EPS 1e-5f
#define SCAN_B ((N_NODES + 255) / 256)   // 196 buckets of 256 nodes
#define BIN_CH 8192
#define BIN_BLOCKS ((N_EDGES + BIN_CH - 1) / BIN_CH)   // 98

typedef __attribute__((ext_vector_type(4))) float f32x4;
typedef __attribute__((ext_vector_type(8))) short short8;

__device__ inline ushort f2bfu(float f) {
    __hip_bfloat16 h = __float2bfloat16(f);
    return __builtin_bit_cast(ushort, h);
}
__device__ inline float bfu2f(ushort u) {
    uint v = ((uint)u) << 16;
    return __builtin_bit_cast(float, v);
}
__device__ inline float lobf(uint u) { return __builtin_bit_cast(float, u << 16); }
__device__ inline float hibf(uint u) { return __builtin_bit_cast(float, u & 0xffff0000u); }

// XOR swizzle: flip bits 4-6 of byte address with row&7 (bijective within a row)
#define SWZ(row, byte) ((byte) ^ (((row) & 7) << 4))

__device__ inline short8 cvt8(float4 a, float4 b) {
    short8 v;
    v[0] = (short)f2bfu(a.x); v[1] = (short)f2bfu(a.y);
    v[2] = (short)f2bfu(a.z); v[3] = (short)f2bfu(a.w);
    v[4] = (short)f2bfu(b.x); v[5] = (short)f2bfu(b.y);
    v[6] = (short)f2bfu(b.z); v[7] = (short)f2bfu(b.w);
    return v;
}

// ---------------- weight prep + per-block bucket partial counts ----------------
// Blocks 0..BIN_BLOCKS-1 additionally count their 8192-edge chunk per 256-node
// bucket and WRITE (not add) partials -> no zeroing, replay-safe.

__global__ __launch_bounds__(256) void prep_w_k(const float* __restrict__ pW,
                                                const float* __restrict__ W1,
                                                const float* __restrict__ W2,
                                                const float* __restrict__ emb,
                                                const int* __restrict__ dst,
                                                short* __restrict__ Wt,
                                                short* __restrict__ W1t,
                                                short* __restrict__ W2t,
                                                ushort* __restrict__ embb,
                                                int* __restrict__ bcnt_part) {
    __shared__ int cnt[SCAN_B];
    int tid = threadIdx.x, bid = blockIdx.x;
    int i = bid * 256 + tid;
    if (i < 128 * 512) {
        int n = i >> 9, k = i & 511;
        Wt[i] = (short)f2bfu(pW[k * 128 + n]);
    }
    if (i < 3 * 128 * 128) {
        int l = i >> 14, rem = i & 16383, n = rem >> 7, k = rem & 127;
        W1t[i] = (short)f2bfu(W1[l * 16384 + k * 128 + n]);
        W2t[i] = (short)f2bfu(W2[l * 16384 + k * 128 + n]);
    }
    if (i < 100 * 128) embb[i] = f2bfu(emb[i]);

    if (bid < BIN_BLOCKS) {
        if (tid < SCAN_B) cnt[tid] = 0;
        __syncthreads();
        int e0 = bid * BIN_CH;
        #pragma unroll
        for (int k = 0; k < BIN_CH / 256; k++) {
            int e = e0 + k * 256 + tid;
            if (e < N_EDGES) atomicAdd(&cnt[dst[e] >> 8], 1);
        }
        __syncthreads();
        if (tid < SCAN_B) bcnt_part[bid * SCAN_B + tid] = cnt[tid];
    }
}

// reduce partials + scan 196 bucket counts -> bucket bases + cursors
__global__ __launch_bounds__(256) void scanb_k(const int* __restrict__ bcnt_part,
                                               int* __restrict__ bbase,
                                               int* __restrict__ bcur) {
    __shared__ int s[256];
    int t = threadIdx.x;
    int v = 0;
    if (t < SCAN_B)
        for (int b = 0; b < BIN_BLOCKS; b++) v += bcnt_part[b * SCAN_B + t];
    s[t] = v;
    __syncthreads();
    for (int d = 1; d < 256; d <<= 1) {
        int u = (t >= d) ? s[t - d] : 0;
        __syncthreads();
        s[t] += u;
        __syncthreads();
    }
    int exc = s[t] - v;   // for t >= SCAN_B this equals total == N_EDGES
    bbase[t] = exc;
    if (t < SCAN_B) bcur[t] = exc;
}

// bin pass: coarse bucket sort (dst>>8), LDS-staged bursts.
// Histogram reuses prep_w_k's per-chunk partial counts (same chunking).
__global__ __launch_bounds__(256) void binpass_k(const int* __restrict__ src,
                                                 const int* __restrict__ dst,
                                                 const int* __restrict__ attr,
                                                 const int* __restrict__ bcnt_part,
                                                 int* __restrict__ bcur,
                                                 int* __restrict__ tmp_ep,
                                                 ushort* __restrict__ tmp_dst) {
    __shared__ int lofs[SCAN_B];
    __shared__ int gbase[SCAN_B];
    __shared__ int cnt2[SCAN_B];
    __shared__ int scan_s[256];
    __shared__ int stage_ep[BIN_CH];      // 32 KB
    __shared__ ushort stage_dst[BIN_CH];  // 16 KB
    int tid = threadIdx.x;
    int e0 = blockIdx.x * BIN_CH;

    int v = (tid < SCAN_B) ? bcnt_part[blockIdx.x * SCAN_B + tid] : 0;
    if (tid < SCAN_B) cnt2[tid] = 0;
    scan_s[tid] = v;
    __syncthreads();
    for (int d = 1; d < 256; d <<= 1) {
        int u = (tid >= d) ? scan_s[tid - d] : 0;
        __syncthreads();
        scan_s[tid] += u;
        __syncthreads();
    }
    if (tid < SCAN_B) lofs[tid] = scan_s[tid] - v;
    int total = scan_s[255];

    if (tid < SCAN_B && v > 0) gbase[tid] = atomicAdd(&bcur[tid], v);
    __syncthreads();

    #pragma unroll
    for (int k = 0; k < BIN_CH / 256; k++) {
        int e = e0 + k * 256 + tid;
        if (e < N_EDGES) {
            int d = dst[e];
            int b = d >> 8;
            int loc = lofs[b] + atomicAdd(&cnt2[b], 1);
            stage_ep[loc] = src[e] | (attr[e] << 16);
            stage_dst[loc] = (ushort)d;
        }
    }
    __syncthreads();

    for (int i = tid; i < total; i += 256) {
        ushort d = stage_dst[i];
        int b = d >> 8;
        int gp = gbase[b] + (i - lofs[b]);
        tmp_ep[gp] = stage_ep[i];
        tmp_dst[gp] = d;
    }
}

// fine pass: per-bucket node offsets + scatter to exact CSR slots
__global__ __launch_bounds__(256) void finepass_k(const int* __restrict__ tmp_ep,
                                                  const ushort* __restrict__ tmp_dst,
                                                  const int* __restrict__ bbase,
                                                  int* __restrict__ offs,
                                                  int* __restrict__ epack) {
    __shared__ int deg[256];
    __shared__ int cur[256];
    __shared__ int wsum[4];
    int tid = threadIdx.x;
    deg[tid] = 0;
    __syncthreads();
    int lo = bbase[blockIdx.x], hi = bbase[blockIdx.x + 1];
    for (int i = lo + tid; i < hi; i += 256)
        atomicAdd(&deg[tmp_dst[i] & 255], 1);
    __syncthreads();
    // exclusive scan of deg[256]
    int lane = tid & 63, w = tid >> 6;
    int v = deg[tid];
    int inc = v;
    #pragma unroll
    for (int d = 1; d < 64; d <<= 1) {
        int u = __shfl_up(inc, d);
        if (lane >= d) inc += u;
    }
    if (lane == 63) wsum[w] = inc;
    __syncthreads();
    int wo = 0;
    #pragma unroll
    for (int k = 0; k < 4; k++) if (k < w) wo += wsum[k];
    int exc = lo + wo + inc - v;
    int node = (blockIdx.x << 8) + tid;
    if (node < N_NODES) offs[node] = exc;
    if (node == N_NODES - 1) offs[N_NODES] = exc + v;
    cur[tid] = exc;
    __syncthreads();
    for (int i = lo + tid; i < hi; i += 256) {
        ushort d = tmp_dst[i];
        int ep = tmp_ep[i];
        int pos = atomicAdd(&cur[d & 255], 1);
        epack[pos] = ep;
    }
}

// ---------------- Projection: x = pep @ W + b  (split-K W-staging, 2 blocks/CU) ----------------
// 256 thr = 4 waves; block tile 128 rows; wave owns 32 rows x 128 cols.
// W staged in two 64KB K-halves -> 2 blocks/CU co-resident (vs 1 at 128KB),
// 391 blocks balance across 256 CUs; A-fragments from global, 4-deep circular.

#define PROJ_ROWS 128
__global__ __launch_bounds__(256) void proj_k(const float* __restrict__ pep,
                                              const short* __restrict__ Wt,
                                              const float* __restrict__ b,
                                              ushort* __restrict__ xb) {
    __shared__ short SW[128 * 256];  // 64 KB; row = out-col n, stride 512B, swizzled
    int tid = threadIdx.x, lane = tid & 63, wid = tid >> 6;

    int m0 = blockIdx.x * PROJ_ROWS + wid * 32;

    const float* arow[2];
    #pragma unroll
    for (int mi = 0; mi < 2; mi++) {
        int node = m0 + mi * 16 + (lane & 15);
        if (node > N_NODES - 1) node = N_NODES - 1;
        arow[mi] = pep + (size_t)node * IN_DIM + ((lane >> 4) << 3);
    }

    f32x4 acc[2][8] = {};
    float4 A[4][2][2];   // 4-deep circular prefetch
    #pragma unroll
    for (int d = 0; d < 4; d++)
        #pragma unroll
        for (int mi = 0; mi < 2; mi++) {
            A[d][mi][0] = *(const float4*)(arow[mi] + d * 32);
            A[d][mi][1] = *(const float4*)(arow[mi] + d * 32 + 4);
        }

    #pragma unroll
    for (int ks = 0; ks < 16; ks++) {
        if ((ks & 7) == 0) {
            int half = ks >> 3;
            if (ks == 8) __syncthreads();   // all waves done reading half 0
            // stage 64KB: Wt[:, half*256 .. +255]; 4096 x 16B chunks
            #pragma unroll
            for (int c = 0; c < 16; c++) {
                int ch = tid + c * 256;
                int row = ch >> 5, kc = (ch & 31) * 16;
                short8 w8 = *(const short8*)((const char*)Wt + row * 1024 + half * 512 + kc);
                *(short8*)((char*)SW + SWZ(row, row * 512 + kc)) = w8;
            }
            __syncthreads();
        }
        int d = ks & 3;
        short8 af0 = cvt8(A[d][0][0], A[d][0][1]);
        short8 af1 = cvt8(A[d][1][0], A[d][1][1]);
        if (ks + 4 < 16) {
            #pragma unroll
            for (int mi = 0; mi < 2; mi++) {
                A[d][mi][0] = *(const float4*)(arow[mi] + (ks + 4) * 32);
                A[d][mi][1] = *(const float4*)(arow[mi] + (ks + 4) * 32 + 4);
            }
        }
        int kb2 = ((ks & 7) * 32 + ((lane >> 4) << 3)) * 2;   // within-half byte offset
        #pragma unroll
        for (int ni = 0; ni < 8; ni++) {
            int n = ni * 16 + (lane & 15);
            short8 bf = *(const short8*)((const char*)SW + SWZ(n, n * 512 + kb2));
            acc[0][ni] = __builtin_amdgcn_mfma_f32_16x16x32_bf16(af0, bf, acc[0][ni], 0, 0, 0);
            acc[1][ni] = __builtin_amdgcn_mfma_f32_16x16x32_bf16(af1, bf, acc[1][ni], 0, 0, 0);
        }
    }

    #pragma unroll
    for (int ni = 0; ni < 8; ni++) {
        int col = ni * 16 + (lane & 15);
        float bb = b[col];
        #pragma unroll
        for (int mi = 0; mi < 2; mi++) {
            int rowb = m0 + mi * 16 + ((lane >> 4) << 2);
            #pragma unroll
            for (int r = 0; r < 4; r++) {
                int node = rowb + r;
                if (node < N_NODES)
                    xb[(size_t)node * H + col] = f2bfu(acc[mi][ni][r] + bb);
            }
        }
    }
}

// ---------------- Edge gather (bf16 x + bf16 emb, 8-deep ILP) ----------------

__global__ __launch_bounds__(256) void gather_k(const ushort* __restrict__ xb,
                                                const int* __restrict__ offs,
                                                const int* __restrict__ epack,
                                                const ushort* __restrict__ embb,
                                                ushort* __restrict__ aggb) {
    int node = (blockIdx.x * 256 + threadIdx.x) >> 6;
    int lane = threadIdx.x & 63;
    if (node >= N_NODES) return;
    int beg = offs[node], end = offs[node + 1];
    float ax = 0.f, ay = 0.f;
    for (int base = beg; base < end; base += 64) {
        int myp = (base + lane < end) ? epack[base + lane] : 0;
        int cnt = min(64, end - base);
        int j = 0;
        for (; j + 8 <= cnt; j += 8) {
            int p0 = __shfl(myp, j),     p1 = __shfl(myp, j + 1);
            int p2 = __shfl(myp, j + 2), p3 = __shfl(myp, j + 3);
            int p4 = __shfl(myp, j + 4), p5 = __shfl(myp, j + 5);
            int p6 = __shfl(myp, j + 6), p7 = __shfl(myp, j + 7);
            uint x0 = *(const uint*)(xb + (size_t)(p0 & 0xffff) * H + lane * 2);
            uint e0 = *(const uint*)(embb + (size_t)(p0 >> 16) * H + lane * 2);
            uint x1 = *(const uint*)(xb + (size_t)(p1 & 0xffff) * H + lane * 2);
            uint e1 = *(const uint*)(embb + (size_t)(p1 >> 16) * H + lane * 2);
            uint x2 = *(const uint*)(xb + (size_t)(p2 & 0xffff) * H + lane * 2);
            uint e2 = *(const uint*)(embb + (size_t)(p2 >> 16) * H + lane * 2);
            uint x3 = *(const uint*)(xb + (size_t)(p3 & 0xffff) * H + lane * 2);
            uint e3 = *(const uint*)(embb + (size_t)(p3 >> 16) * H + lane * 2);
            uint x4 = *(const uint*)(xb + (size_t)(p4 & 0xffff) * H + lane * 2);
            uint e4 = *(const uint*)(embb + (size_t)(p4 >> 16) * H + lane * 2);
            uint x5 = *(const uint*)(xb + (size_t)(p5 & 0xffff) * H + lane * 2);
            uint e5 = *(const uint*)(embb + (size_t)(p5 >> 16) * H + lane * 2);
            uint x6 = *(const uint*)(xb + (size_t)(p6 & 0xffff) * H + lane * 2);
            uint e6 = *(const uint*)(embb + (size_t)(p6 >> 16) * H + lane * 2);
            uint x7 = *(const uint*)(xb + (size_t)(p7 & 0xffff) * H + lane * 2);
            uint e7 = *(const uint*)(embb + (size_t)(p7 >> 16) * H + lane * 2);
            ax += fmaxf(lobf(x0) + lobf(e0), 0.f); ay += fmaxf(hibf(x0) + hibf(e0), 0.f);
            ax += fmaxf(lobf(x1) + lobf(e1), 0.f); ay += fmaxf(hibf(x1) + hibf(e1), 0.f);
            ax += fmaxf(lobf(x2) + lobf(e2), 0.f); ay += fmaxf(hibf(x2) + hibf(e2), 0.f);
            ax += fmaxf(lobf(x3) + lobf(e3), 0.f); ay += fmaxf(hibf(x3) + hibf(e3), 0.f);
            ax += fmaxf(lobf(x4) + lobf(e4), 0.f); ay += fmaxf(hibf(x4) + hibf(e4), 0.f);
            ax += fmaxf(lobf(x5) + lobf(e5), 0.f); ay += fmaxf(hibf(x5) + hibf(e5), 0.f);
            ax += fmaxf(lobf(x6) + lobf(e6), 0.f); ay += fmaxf(hibf(x6) + hibf(e6), 0.f);
            ax += fmaxf(lobf(x7) + lobf(e7), 0.f); ay += fmaxf(hibf(x7) + hibf(e7), 0.f);
        }
        for (; j + 4 <= cnt; j += 4) {
            int p0 = __shfl(myp, j), p1 = __shfl(myp, j + 1);
            int p2 = __shfl(myp, j + 2), p3 = __shfl(myp, j + 3);
            uint x0 = *(const uint*)(xb + (size_t)(p0 & 0xffff) * H + lane * 2);
            uint e0 = *(const uint*)(embb + (size_t)(p0 >> 16) * H + lane * 2);
            uint x1 = *(const uint*)(xb + (size_t)(p1 & 0xffff) * H + lane * 2);
            uint e1 = *(const uint*)(embb + (size_t)(p1 >> 16) * H + lane * 2);
            uint x2 = *(const uint*)(xb + (size_t)(p2 & 0xffff) * H + lane * 2);
            uint e2 = *(const uint*)(embb + (size_t)(p2 >> 16) * H + lane * 2);
            uint x3 = *(const uint*)(xb + (size_t)(p3 & 0xffff) * H + lane * 2);
            uint e3 = *(const uint*)(embb + (size_t)(p3 >> 16) * H + lane * 2);
            ax += fmaxf(lobf(x0) + lobf(e0), 0.f); ay += fmaxf(hibf(x0) + hibf(e0), 0.f);
            ax += fmaxf(lobf(x1) + lobf(e1), 0.f); ay += fmaxf(hibf(x1) + hibf(e1), 0.f);
            ax += fmaxf(lobf(x2) + lobf(e2), 0.f); ay += fmaxf(hibf(x2) + hibf(e2), 0.f);
            ax += fmaxf(lobf(x3) + lobf(e3), 0.f); ay += fmaxf(hibf(x3) + hibf(e3), 0.f);
        }
        for (; j < cnt; j++) {
            int p = __shfl(myp, j);
            uint xv = *(const uint*)(xb + (size_t)(p & 0xffff) * H + lane * 2);
            uint ev = *(const uint*)(embb + (size_t)(p >> 16) * H + lane * 2);
            ax += fmaxf(lobf(xv) + lobf(ev), 0.f);
            ay += fmaxf(hibf(xv) + hibf(ev), 0.f);
        }
    }
    uint packed = (uint)f2bfu(ax) | ((uint)f2bfu(ay) << 16);
    *(uint*)(aggb + (size_t)node * H + lane * 2) = packed;
}

// ---------------- Fused MLP + residual (MFMA bf16, 64-row tiles); optional fused LN ----
// bf16 residual chain: h from xb+aggb; epilogue residual re-reads xb; writes xb in place.

#define MLP_ROWS 64
__global__ __launch_bounds__(256) void mlp_k(ushort* __restrict__ xb,
                                             const ushort* __restrict__ aggb,
                                             const short* __restrict__ W1t,
                                             const float* __restrict__ b1,
                                             const short* __restrict__ W2t,
                                             const float* __restrict__ b2,
                                             const float* __restrict__ gamma,
                                             const float* __restrict__ beta,
                                             float* __restrict__ out,
                                             int do_ln) {
    __shared__ short S[MLP_ROWS * 128];  // 16 KB
    __shared__ short Wb[128 * 128];      // 32 KB (reused as fp32 [64][128] for LN)
    int tid = threadIdx.x, lane = tid & 63, wid = tid >> 6;
    int wr = wid >> 1, wc = wid & 1;
    int m0 = blockIdx.x * MLP_ROWS;

    // stage h = bf16(x_bf16 + agg_bf16)
    #pragma unroll
    for (int c = 0; c < 4; c++) {
        int ch = tid + c * 256;
        int row = ch >> 4, k8 = (ch & 15) * 8;
        int node = m0 + row;
        short8 hv;
        if (node < N_NODES) {
            short8 xv = *(const short8*)(xb + (size_t)node * H + k8);
            short8 ag = *(const short8*)(aggb + (size_t)node * H + k8);
            #pragma unroll
            for (int q = 0; q < 8; q++)
                hv[q] = (short)f2bfu(bfu2f((ushort)xv[q]) + bfu2f((ushort)ag[q]));
        } else {
            hv = (short8)0;
        }
        *(short8*)((char*)S + SWZ(row, row * 256 + k8 * 2)) = hv;
    }
    #pragma unroll
    for (int c = 0; c < 8; c++) {
        int ch = tid + c * 256;
        int row = ch >> 4, k8 = (ch & 15) * 8;
        short8 w = *(const short8*)(W1t + row * H + k8);
        *(short8*)((char*)Wb + SWZ(row, row * 256 + k8 * 2)) = w;
    }
    short8 wreg2[8];
    #pragma unroll
    for (int c = 0; c < 8; c++) {
        int ch = tid + c * 256;
        int row = ch >> 4, k8 = (ch & 15) * 8;
        wreg2[c] = *(const short8*)(W2t + row * H + k8);
    }
    __syncthreads();

    f32x4 a1[2][4] = {};
    #pragma unroll
    for (int ks = 0; ks < 4; ks++) {
        int kb = ks * 32 + (lane >> 4) * 8;
        short8 af[2], bfr[4];
        #pragma unroll
        for (int mi = 0; mi < 2; mi++) {
            int r = wr * 32 + mi * 16 + (lane & 15);
            af[mi] = *(const short8*)((const char*)S + SWZ(r, r * 256 + kb * 2));
        }
        #pragma unroll
        for (int ni = 0; ni < 4; ni++) {
            int n = wc * 64 + ni * 16 + (lane & 15);
            bfr[ni] = *(const short8*)((const char*)Wb + SWZ(n, n * 256 + kb * 2));
        }
        #pragma unroll
        for (int mi = 0; mi < 2; mi++)
            #pragma unroll
            for (int ni = 0; ni < 4; ni++)
                a1[mi][ni] = __builtin_amdgcn_mfma_f32_16x16x32_bf16(
                    af[mi], bfr[ni], a1[mi][ni], 0, 0, 0);
    }
    __syncthreads();

    #pragma unroll
    for (int ni = 0; ni < 4; ni++) {
        int n = wc * 64 + ni * 16 + (lane & 15);
        float bb = b1[n];
        #pragma unroll
        for (int mi = 0; mi < 2; mi++) {
            int mrow = wr * 32 + mi * 16 + ((lane >> 4) << 2);
            #pragma unroll
            for (int r = 0; r < 4; r++) {
                int m = mrow + r;
                float tv = fmaxf(a1[mi][ni][r] + bb, 0.f);
                *(ushort*)((char*)S + SWZ(m, m * 256 + n * 2)) = f2bfu(tv);
            }
        }
    }
    #pragma unroll
    for (int c = 0; c < 8; c++) {
        int ch = tid + c * 256;
        int row = ch >> 4, k8 = (ch & 15) * 8;
        *(short8*)((char*)Wb + SWZ(row, row * 256 + k8 * 2)) = wreg2[c];
    }
    __syncthreads();

    f32x4 a2[4][2] = {};
    #pragma unroll
    for (int ks = 0; ks < 4; ks++) {
        int kb = ks * 32 + (lane >> 4) * 8;
        short8 af[4], bfr[2];
        #pragma unroll
        for (int mi = 0; mi < 4; mi++) {
            int n2 = wr * 64 + mi * 16 + (lane & 15);
            af[mi] = *(const short8*)((const char*)Wb + SWZ(n2, n2 * 256 + kb * 2));
        }
        #pragma unroll
        for (int ni = 0; ni < 2; ni++) {
            int m = wc * 32 + ni * 16 + (lane & 15);
            bfr[ni] = *(const short8*)((const char*)S + SWZ(m, m * 256 + kb * 2));
        }
        #pragma unroll
        for (int mi = 0; mi < 4; mi++)
            #pragma unroll
            for (int ni = 0; ni < 2; ni++)
                a2[mi][ni] = __builtin_amdgcn_mfma_f32_16x16x32_bf16(
                    af[mi], bfr[ni], a2[mi][ni], 0, 0, 0);
    }

    if (!do_ln) {
        #pragma unroll
        for (int ni = 0; ni < 2; ni++) {
            int node = m0 + wc * 32 + ni * 16 + (lane & 15);
            if (node >= N_NODES) continue;
            #pragma unroll
            for (int mi = 0; mi < 4; mi++) {
                int n2b = wr * 64 + mi * 16 + ((lane >> 4) << 2);
                ulong xr = *(const ulong*)(xb + (size_t)node * H + n2b);
                const ushort* xp = (const ushort*)&xr;
                float4 bb = *(const float4*)(b2 + n2b);
                ushort us[4];
                us[0] = f2bfu(a2[mi][ni][0] + bb.x + bfu2f(xp[0]));
                us[1] = f2bfu(a2[mi][ni][1] + bb.y + bfu2f(xp[1]));
                us[2] = f2bfu(a2[mi][ni][2] + bb.z + bfu2f(xp[2]));
                us[3] = f2bfu(a2[mi][ni][3] + bb.w + bfu2f(xp[3]));
                *(ulong*)(xb + (size_t)node * H + n2b) = *(ulong*)us;
            }
        }
    } else {
        // last layer: keep fp32 pre-LN value in LDS (reuse Wb) and LayerNorm
        float* F = (float*)Wb;
        __syncthreads();
        #pragma unroll
        for (int ni = 0; ni < 2; ni++) {
            int nl = wc * 32 + ni * 16 + (lane & 15);   // 0..63
            int node = m0 + nl;
            #pragma unroll
            for (int mi = 0; mi < 4; mi++) {
                int n2b = wr * 64 + mi * 16 + ((lane >> 4) << 2);
                float4 o = {0.f, 0.f, 0.f, 0.f};
                if (node < N_NODES) {
                    ulong xr = *(const ulong*)(xb + (size_t)node * H + n2b);
                    const ushort* xp = (const ushort*)&xr;
                    float4 bb = *(const float4*)(b2 + n2b);
                    o.x = a2[mi][ni][0] + bb.x + bfu2f(xp[0]);
                    o.y = a2[mi][ni][1] + bb.y + bfu2f(xp[1]);
                    o.z = a2[mi][ni][2] + bb.z + bfu2f(xp[2]);
                    o.w = a2[mi][ni][3] + bb.w + bfu2f(xp[3]);
                }
                *(float4*)((char*)F + SWZ(nl, nl * 512 + n2b * 4)) = o;
            }
        }
        __syncthreads();
        float2 gm = ((const float2*)gamma)[lane];
        float2 bt = ((const float2*)beta)[lane];
        for (int i = 0; i < 16; i++) {
            int row = wid * 16 + i;
            int node = m0 + row;
            if (node >= N_NODES) break;   // wave-uniform
            float2 v = *(float2*)((char*)F + SWZ(row, row * 512 + lane * 8));
            float s = v.x + v.y;
            #pragma unroll
            for (int d = 1; d < 64; d <<= 1) s += __shfl_xor(s, d);
            float mu = s * (1.f / 128.f);
            float dx = v.x - mu, dy = v.y - mu;
            float q = dx * dx + dy * dy;
            #pragma unroll
            for (int d = 1; d < 64; d <<= 1) q += __shfl_xor(q, d);
            float inv = rsqrtf(q * (1.f / 128.f) + LN_EPS);
            float2 o2;
            o2.x = gm.x * dx * inv + bt.x;
            o2.y = gm.y * dy * inv + bt.y;
            ((float2*)(out + (size_t)node * H))[lane] = o2;
        }
    }
}

// ---------------- launcher ----------------

extern "C" void kernel_launch(void* const* d_in, const int* in_sizes, int n_in,
                              void* d_out, int out_size, void* d_ws, size_t ws_size,
                              hipStream_t stream) {
    const float* pep    = (const float*)d_in[0];
    const float* proj_W = (const float*)d_in[1];
    const float* proj_b = (const float*)d_in[2];
    const float* emb    = (const float*)d_in[3];
    const float* cW1    = (const float*)d_in[4];
    const float* cb1    = (const float*)d_in[5];
    const float* cW2    = (const float*)d_in[6];
    const float* cb2    = (const float*)d_in[7];
    const float* gamma  = (const float*)d_in[8];
    const float* beta   = (const float*)d_in[9];
    const int*   eidx   = (const int*)d_in[10];
    const int*   attr   = (const int*)d_in[11];
    const int* src = eidx;
    const int* dst = eidx + N_EDGES;

    char* w = (char*)d_ws;
    ushort* xb     = (ushort*)w;            w += (size_t)N_NODES * H * 2;
    ushort* aggb   = (ushort*)w;            w += (size_t)N_NODES * H * 2;
    short*  Wt     = (short*)w;             w += 128 * 512 * 2;
    short*  W1t    = (short*)w;             w += 3 * 128 * 128 * 2;
    short*  W2t    = (short*)w;             w += 3 * 128 * 128 * 2;
    ushort* embb   = (ushort*)w;            w += 100 * 128 * 2;
    int*    offs   = (int*)w;               w += (N_NODES + 16) * 4;
    int*    bcnt_part = (int*)w;            w += (size_t)BIN_BLOCKS * SCAN_B * 4;
    int*    bbase  = (int*)w;               w += 260 * 4;
    int*    bcur   = (int*)w;               w += 256 * 4;
    int*    epack  = (int*)w;               w += (size_t)N_EDGES * 4;
    int*    tmp_ep = (int*)w;               w += (size_t)N_EDGES * 4;
    ushort* tmp_dst = (ushort*)w;           w += (size_t)N_EDGES * 2;

    float* out = (float*)d_out;

    prep_w_k<<<256, 256, 0, stream>>>(proj_W, cW1, cW2, emb, dst,
                                      Wt, W1t, W2t, embb, bcnt_part);
    scanb_k<<<1, 256, 0, stream>>>(bcnt_part, bbase, bcur);
    binpass_k<<<BIN_BLOCKS, 256, 0, stream>>>(src, dst, attr, bcnt_part, bcur,
                                              tmp_ep, tmp_dst);
    finepass_k<<<SCAN_B, 256, 0, stream>>>(tmp_ep, tmp_dst, bbase, offs, epack);

    proj_k<<<(N_NODES + PROJ_ROWS - 1) / PROJ_ROWS, 256, 0, stream>>>(pep, Wt, proj_b, xb);

    for (int l = 0; l < N_LAYERS; l++) {
        gather_k<<<(N_NODES * 64 + 255) / 256, 256, 0, stream>>>(
            xb, offs, epack, embb, aggb);
        mlp_k<<<(N_NODES + MLP_ROWS - 1) / MLP_ROWS, 256, 0, stream>>>(
            xb, aggb,
            W1t + (size_t)l * H * H, cb1 + (size_t)l * H,
            W2t + (size_t)l * H * H, cb2 + (size_t)l * H,
            gamma, beta, out,
            (l == N_LAYERS - 1) ? 1 : 0);
    }
}

// Round 14
// 255.517 us; speedup vs baseline: 1.0393x; 1.0393x over previous
//
#include <hip/hip_runtime.h>
#include <hip/hip_bf16.h>

#define N_NODES 50000
#define N_EDGES 800000
#define H 128
#define IN_DIM 512
#define N_LAYERS 3
#define LN_EPS 1e-5f
#define SCAN_B ((N_NODES + 255) / 256)   // 196 buckets of 256 nodes
#define BIN_CH 8192
#define BIN_BLOCKS ((N_EDGES + BIN_CH - 1) / BIN_CH)   // 98

typedef __attribute__((ext_vector_type(4))) float f32x4;
typedef __attribute__((ext_vector_type(8))) short short8;

__device__ inline ushort f2bfu(float f) {
    __hip_bfloat16 h = __float2bfloat16(f);
    return __builtin_bit_cast(ushort, h);
}
__device__ inline float bfu2f(ushort u) {
    uint v = ((uint)u) << 16;
    return __builtin_bit_cast(float, v);
}
__device__ inline float lobf(uint u) { return __builtin_bit_cast(float, u << 16); }
__device__ inline float hibf(uint u) { return __builtin_bit_cast(float, u & 0xffff0000u); }

// XOR swizzle: flip bits 4-6 of byte address with row&7 (bijective within a row)
#define SWZ(row, byte) ((byte) ^ (((row) & 7) << 4))

__device__ inline short8 cvt8(float4 a, float4 b) {
    short8 v;
    v[0] = (short)f2bfu(a.x); v[1] = (short)f2bfu(a.y);
    v[2] = (short)f2bfu(a.z); v[3] = (short)f2bfu(a.w);
    v[4] = (short)f2bfu(b.x); v[5] = (short)f2bfu(b.y);
    v[6] = (short)f2bfu(b.z); v[7] = (short)f2bfu(b.w);
    return v;
}

// ---------------- weight prep + per-block bucket partial counts ----------------
// Blocks 0..BIN_BLOCKS-1 additionally count their 8192-edge chunk per 256-node
// bucket and WRITE (not add) partials -> no zeroing, replay-safe.

__global__ __launch_bounds__(256) void prep_w_k(const float* __restrict__ pW,
                                                const float* __restrict__ W1,
                                                const float* __restrict__ W2,
                                                const float* __restrict__ emb,
                                                const int* __restrict__ dst,
                                                short* __restrict__ Wt,
                                                short* __restrict__ W1t,
                                                short* __restrict__ W2t,
                                                ushort* __restrict__ embb,
                                                int* __restrict__ bcnt_part) {
    __shared__ int cnt[SCAN_B];
    int tid = threadIdx.x, bid = blockIdx.x;
    int i = bid * 256 + tid;
    if (i < 128 * 512) {
        int n = i >> 9, k = i & 511;
        Wt[i] = (short)f2bfu(pW[k * 128 + n]);
    }
    if (i < 3 * 128 * 128) {
        int l = i >> 14, rem = i & 16383, n = rem >> 7, k = rem & 127;
        W1t[i] = (short)f2bfu(W1[l * 16384 + k * 128 + n]);
        W2t[i] = (short)f2bfu(W2[l * 16384 + k * 128 + n]);
    }
    if (i < 100 * 128) embb[i] = f2bfu(emb[i]);

    if (bid < BIN_BLOCKS) {
        if (tid < SCAN_B) cnt[tid] = 0;
        __syncthreads();
        int e0 = bid * BIN_CH;
        #pragma unroll
        for (int k = 0; k < BIN_CH / 256; k++) {
            int e = e0 + k * 256 + tid;
            if (e < N_EDGES) atomicAdd(&cnt[dst[e] >> 8], 1);
        }
        __syncthreads();
        if (tid < SCAN_B) bcnt_part[bid * SCAN_B + tid] = cnt[tid];
    }
}

// reduce partials + scan 196 bucket counts -> bucket bases + cursors
__global__ __launch_bounds__(256) void scanb_k(const int* __restrict__ bcnt_part,
                                               int* __restrict__ bbase,
                                               int* __restrict__ bcur) {
    __shared__ int s[256];
    int t = threadIdx.x;
    int v = 0;
    if (t < SCAN_B)
        for (int b = 0; b < BIN_BLOCKS; b++) v += bcnt_part[b * SCAN_B + t];
    s[t] = v;
    __syncthreads();
    for (int d = 1; d < 256; d <<= 1) {
        int u = (t >= d) ? s[t - d] : 0;
        __syncthreads();
        s[t] += u;
        __syncthreads();
    }
    int exc = s[t] - v;   // for t >= SCAN_B this equals total == N_EDGES
    bbase[t] = exc;
    if (t < SCAN_B) bcur[t] = exc;
}

// bin pass: coarse bucket sort (dst>>8), LDS-staged bursts.
// Histogram reuses prep_w_k's per-chunk partial counts (same chunking).
__global__ __launch_bounds__(256) void binpass_k(const int* __restrict__ src,
                                                 const int* __restrict__ dst,
                                                 const int* __restrict__ attr,
                                                 const int* __restrict__ bcnt_part,
                                                 int* __restrict__ bcur,
                                                 int* __restrict__ tmp_ep,
                                                 ushort* __restrict__ tmp_dst) {
    __shared__ int lofs[SCAN_B];
    __shared__ int gbase[SCAN_B];
    __shared__ int cnt2[SCAN_B];
    __shared__ int scan_s[256];
    __shared__ int stage_ep[BIN_CH];      // 32 KB
    __shared__ ushort stage_dst[BIN_CH];  // 16 KB
    int tid = threadIdx.x;
    int e0 = blockIdx.x * BIN_CH;

    int v = (tid < SCAN_B) ? bcnt_part[blockIdx.x * SCAN_B + tid] : 0;
    if (tid < SCAN_B) cnt2[tid] = 0;
    scan_s[tid] = v;
    __syncthreads();
    for (int d = 1; d < 256; d <<= 1) {
        int u = (tid >= d) ? scan_s[tid - d] : 0;
        __syncthreads();
        scan_s[tid] += u;
        __syncthreads();
    }
    if (tid < SCAN_B) lofs[tid] = scan_s[tid] - v;
    int total = scan_s[255];

    if (tid < SCAN_B && v > 0) gbase[tid] = atomicAdd(&bcur[tid], v);
    __syncthreads();

    #pragma unroll
    for (int k = 0; k < BIN_CH / 256; k++) {
        int e = e0 + k * 256 + tid;
        if (e < N_EDGES) {
            int d = dst[e];
            int b = d >> 8;
            int loc = lofs[b] + atomicAdd(&cnt2[b], 1);
            stage_ep[loc] = src[e] | (attr[e] << 16);
            stage_dst[loc] = (ushort)d;
        }
    }
    __syncthreads();

    for (int i = tid; i < total; i += 256) {
        ushort d = stage_dst[i];
        int b = d >> 8;
        int gp = gbase[b] + (i - lofs[b]);
        tmp_ep[gp] = stage_ep[i];
        tmp_dst[gp] = d;
    }
}

// fine pass: per-bucket node offsets + scatter to exact CSR slots
__global__ __launch_bounds__(256) void finepass_k(const int* __restrict__ tmp_ep,
                                                  const ushort* __restrict__ tmp_dst,
                                                  const int* __restrict__ bbase,
                                                  int* __restrict__ offs,
                                                  int* __restrict__ epack) {
    __shared__ int deg[256];
    __shared__ int cur[256];
    __shared__ int wsum[4];
    int tid = threadIdx.x;
    deg[tid] = 0;
    __syncthreads();
    int lo = bbase[blockIdx.x], hi = bbase[blockIdx.x + 1];
    for (int i = lo + tid; i < hi; i += 256)
        atomicAdd(&deg[tmp_dst[i] & 255], 1);
    __syncthreads();
    // exclusive scan of deg[256]
    int lane = tid & 63, w = tid >> 6;
    int v = deg[tid];
    int inc = v;
    #pragma unroll
    for (int d = 1; d < 64; d <<= 1) {
        int u = __shfl_up(inc, d);
        if (lane >= d) inc += u;
    }
    if (lane == 63) wsum[w] = inc;
    __syncthreads();
    int wo = 0;
    #pragma unroll
    for (int k = 0; k < 4; k++) if (k < w) wo += wsum[k];
    int exc = lo + wo + inc - v;
    int node = (blockIdx.x << 8) + tid;
    if (node < N_NODES) offs[node] = exc;
    if (node == N_NODES - 1) offs[N_NODES] = exc + v;
    cur[tid] = exc;
    __syncthreads();
    for (int i = lo + tid; i < hi; i += 256) {
        ushort d = tmp_dst[i];
        int ep = tmp_ep[i];
        int pos = atomicAdd(&cur[d & 255], 1);
        epack[pos] = ep;
    }
}

// ---------------- Projection: x = pep @ W + b  (W-resident, 4-deep prefetch; R12 form) ----------------
// 512 thr = 8 waves; block tile 256 rows; wave owns 32 rows x 128 cols.
// Full Wt (128KB) staged in LDS once; A-fragments loaded straight from pep,
// circular-buffered 4 K-steps deep (~1000+ cycles ahead, covers HBM latency).

__global__ __launch_bounds__(512) void proj_k(const float* __restrict__ pep,
                                              const short* __restrict__ Wt,
                                              const float* __restrict__ b,
                                              ushort* __restrict__ xb) {
    __shared__ short SW[128 * 512];  // 128 KB; row = out-col n, stride 1024B, swizzled
    int tid = threadIdx.x, lane = tid & 63, wid = tid >> 6;

    #pragma unroll
    for (int c = 0; c < 16; c++) {
        int ch = tid + c * 512;
        int row = ch >> 6, kc = (ch & 63) * 16;
        short8 w = *(const short8*)((const char*)Wt + row * 1024 + kc);
        *(short8*)((char*)SW + SWZ(row, row * 1024 + kc)) = w;
    }
    __syncthreads();

    int m0 = blockIdx.x * 256 + wid * 32;

    const float* arow[2];
    #pragma unroll
    for (int mi = 0; mi < 2; mi++) {
        int node = m0 + mi * 16 + (lane & 15);
        if (node > N_NODES - 1) node = N_NODES - 1;
        arow[mi] = pep + (size_t)node * IN_DIM + ((lane >> 4) << 3);
    }

    f32x4 acc[2][8] = {};
    float4 A[4][2][2];   // 4-deep circular prefetch
    #pragma unroll
    for (int d = 0; d < 4; d++)
        #pragma unroll
        for (int mi = 0; mi < 2; mi++) {
            A[d][mi][0] = *(const float4*)(arow[mi] + d * 32);
            A[d][mi][1] = *(const float4*)(arow[mi] + d * 32 + 4);
        }

    #pragma unroll
    for (int ks = 0; ks < 16; ks++) {
        int d = ks & 3;
        short8 af0 = cvt8(A[d][0][0], A[d][0][1]);
        short8 af1 = cvt8(A[d][1][0], A[d][1][1]);
        if (ks + 4 < 16) {
            #pragma unroll
            for (int mi = 0; mi < 2; mi++) {
                A[d][mi][0] = *(const float4*)(arow[mi] + (ks + 4) * 32);
                A[d][mi][1] = *(const float4*)(arow[mi] + (ks + 4) * 32 + 4);
            }
        }
        int kb2 = (ks * 32 + ((lane >> 4) << 3)) * 2;
        #pragma unroll
        for (int ni = 0; ni < 8; ni++) {
            int n = ni * 16 + (lane & 15);
            short8 bf = *(const short8*)((const char*)SW + SWZ(n, n * 1024 + kb2));
            acc[0][ni] = __builtin_amdgcn_mfma_f32_16x16x32_bf16(af0, bf, acc[0][ni], 0, 0, 0);
            acc[1][ni] = __builtin_amdgcn_mfma_f32_16x16x32_bf16(af1, bf, acc[1][ni], 0, 0, 0);
        }
    }

    #pragma unroll
    for (int ni = 0; ni < 8; ni++) {
        int col = ni * 16 + (lane & 15);
        float bb = b[col];
        #pragma unroll
        for (int mi = 0; mi < 2; mi++) {
            int rowb = m0 + mi * 16 + ((lane >> 4) << 2);
            #pragma unroll
            for (int r = 0; r < 4; r++) {
                int node = rowb + r;
                if (node < N_NODES)
                    xb[(size_t)node * H + col] = f2bfu(acc[mi][ni][r] + bb);
            }
        }
    }
}

// ---------------- Edge gather (bf16 x + bf16 emb, 8-deep ILP) ----------------

__global__ __launch_bounds__(256) void gather_k(const ushort* __restrict__ xb,
                                                const int* __restrict__ offs,
                                                const int* __restrict__ epack,
                                                const ushort* __restrict__ embb,
                                                ushort* __restrict__ aggb) {
    int node = (blockIdx.x * 256 + threadIdx.x) >> 6;
    int lane = threadIdx.x & 63;
    if (node >= N_NODES) return;
    int beg = offs[node], end = offs[node + 1];
    float ax = 0.f, ay = 0.f;
    for (int base = beg; base < end; base += 64) {
        int myp = (base + lane < end) ? epack[base + lane] : 0;
        int cnt = min(64, end - base);
        int j = 0;
        for (; j + 8 <= cnt; j += 8) {
            int p0 = __shfl(myp, j),     p1 = __shfl(myp, j + 1);
            int p2 = __shfl(myp, j + 2), p3 = __shfl(myp, j + 3);
            int p4 = __shfl(myp, j + 4), p5 = __shfl(myp, j + 5);
            int p6 = __shfl(myp, j + 6), p7 = __shfl(myp, j + 7);
            uint x0 = *(const uint*)(xb + (size_t)(p0 & 0xffff) * H + lane * 2);
            uint e0 = *(const uint*)(embb + (size_t)(p0 >> 16) * H + lane * 2);
            uint x1 = *(const uint*)(xb + (size_t)(p1 & 0xffff) * H + lane * 2);
            uint e1 = *(const uint*)(embb + (size_t)(p1 >> 16) * H + lane * 2);
            uint x2 = *(const uint*)(xb + (size_t)(p2 & 0xffff) * H + lane * 2);
            uint e2 = *(const uint*)(embb + (size_t)(p2 >> 16) * H + lane * 2);
            uint x3 = *(const uint*)(xb + (size_t)(p3 & 0xffff) * H + lane * 2);
            uint e3 = *(const uint*)(embb + (size_t)(p3 >> 16) * H + lane * 2);
            uint x4 = *(const uint*)(xb + (size_t)(p4 & 0xffff) * H + lane * 2);
            uint e4 = *(const uint*)(embb + (size_t)(p4 >> 16) * H + lane * 2);
            uint x5 = *(const uint*)(xb + (size_t)(p5 & 0xffff) * H + lane * 2);
            uint e5 = *(const uint*)(embb + (size_t)(p5 >> 16) * H + lane * 2);
            uint x6 = *(const uint*)(xb + (size_t)(p6 & 0xffff) * H + lane * 2);
            uint e6 = *(const uint*)(embb + (size_t)(p6 >> 16) * H + lane * 2);
            uint x7 = *(const uint*)(xb + (size_t)(p7 & 0xffff) * H + lane * 2);
            uint e7 = *(const uint*)(embb + (size_t)(p7 >> 16) * H + lane * 2);
            ax += fmaxf(lobf(x0) + lobf(e0), 0.f); ay += fmaxf(hibf(x0) + hibf(e0), 0.f);
            ax += fmaxf(lobf(x1) + lobf(e1), 0.f); ay += fmaxf(hibf(x1) + hibf(e1), 0.f);
            ax += fmaxf(lobf(x2) + lobf(e2), 0.f); ay += fmaxf(hibf(x2) + hibf(e2), 0.f);
            ax += fmaxf(lobf(x3) + lobf(e3), 0.f); ay += fmaxf(hibf(x3) + hibf(e3), 0.f);
            ax += fmaxf(lobf(x4) + lobf(e4), 0.f); ay += fmaxf(hibf(x4) + hibf(e4), 0.f);
            ax += fmaxf(lobf(x5) + lobf(e5), 0.f); ay += fmaxf(hibf(x5) + hibf(e5), 0.f);
            ax += fmaxf(lobf(x6) + lobf(e6), 0.f); ay += fmaxf(hibf(x6) + hibf(e6), 0.f);
            ax += fmaxf(lobf(x7) + lobf(e7), 0.f); ay += fmaxf(hibf(x7) + hibf(e7), 0.f);
        }
        for (; j + 4 <= cnt; j += 4) {
            int p0 = __shfl(myp, j), p1 = __shfl(myp, j + 1);
            int p2 = __shfl(myp, j + 2), p3 = __shfl(myp, j + 3);
            uint x0 = *(const uint*)(xb + (size_t)(p0 & 0xffff) * H + lane * 2);
            uint e0 = *(const uint*)(embb + (size_t)(p0 >> 16) * H + lane * 2);
            uint x1 = *(const uint*)(xb + (size_t)(p1 & 0xffff) * H + lane * 2);
            uint e1 = *(const uint*)(embb + (size_t)(p1 >> 16) * H + lane * 2);
            uint x2 = *(const uint*)(xb + (size_t)(p2 & 0xffff) * H + lane * 2);
            uint e2 = *(const uint*)(embb + (size_t)(p2 >> 16) * H + lane * 2);
            uint x3 = *(const uint*)(xb + (size_t)(p3 & 0xffff) * H + lane * 2);
            uint e3 = *(const uint*)(embb + (size_t)(p3 >> 16) * H + lane * 2);
            ax += fmaxf(lobf(x0) + lobf(e0), 0.f); ay += fmaxf(hibf(x0) + hibf(e0), 0.f);
            ax += fmaxf(lobf(x1) + lobf(e1), 0.f); ay += fmaxf(hibf(x1) + hibf(e1), 0.f);
            ax += fmaxf(lobf(x2) + lobf(e2), 0.f); ay += fmaxf(hibf(x2) + hibf(e2), 0.f);
            ax += fmaxf(lobf(x3) + lobf(e3), 0.f); ay += fmaxf(hibf(x3) + hibf(e3), 0.f);
        }
        for (; j < cnt; j++) {
            int p = __shfl(myp, j);
            uint xv = *(const uint*)(xb + (size_t)(p & 0xffff) * H + lane * 2);
            uint ev = *(const uint*)(embb + (size_t)(p >> 16) * H + lane * 2);
            ax += fmaxf(lobf(xv) + lobf(ev), 0.f);
            ay += fmaxf(hibf(xv) + hibf(ev), 0.f);
        }
    }
    uint packed = (uint)f2bfu(ax) | ((uint)f2bfu(ay) << 16);
    *(uint*)(aggb + (size_t)node * H + lane * 2) = packed;
}

// ---------------- Fused MLP + residual (MFMA bf16, 64-row tiles); optional fused LN ----
// bf16 residual chain: h from xb+aggb; epilogue residual re-reads xb; writes xb in place.

#define MLP_ROWS 64
__global__ __launch_bounds__(256) void mlp_k(ushort* __restrict__ xb,
                                             const ushort* __restrict__ aggb,
                                             const short* __restrict__ W1t,
                                             const float* __restrict__ b1,
                                             const short* __restrict__ W2t,
                                             const float* __restrict__ b2,
                                             const float* __restrict__ gamma,
                                             const float* __restrict__ beta,
                                             float* __restrict__ out,
                                             int do_ln) {
    __shared__ short S[MLP_ROWS * 128];  // 16 KB
    __shared__ short Wb[128 * 128];      // 32 KB (reused as fp32 [64][128] for LN)
    int tid = threadIdx.x, lane = tid & 63, wid = tid >> 6;
    int wr = wid >> 1, wc = wid & 1;
    int m0 = blockIdx.x * MLP_ROWS;

    // stage h = bf16(x_bf16 + agg_bf16)
    #pragma unroll
    for (int c = 0; c < 4; c++) {
        int ch = tid + c * 256;
        int row = ch >> 4, k8 = (ch & 15) * 8;
        int node = m0 + row;
        short8 hv;
        if (node < N_NODES) {
            short8 xv = *(const short8*)(xb + (size_t)node * H + k8);
            short8 ag = *(const short8*)(aggb + (size_t)node * H + k8);
            #pragma unroll
            for (int q = 0; q < 8; q++)
                hv[q] = (short)f2bfu(bfu2f((ushort)xv[q]) + bfu2f((ushort)ag[q]));
        } else {
            hv = (short8)0;
        }
        *(short8*)((char*)S + SWZ(row, row * 256 + k8 * 2)) = hv;
    }
    #pragma unroll
    for (int c = 0; c < 8; c++) {
        int ch = tid + c * 256;
        int row = ch >> 4, k8 = (ch & 15) * 8;
        short8 w = *(const short8*)(W1t + row * H + k8);
        *(short8*)((char*)Wb + SWZ(row, row * 256 + k8 * 2)) = w;
    }
    short8 wreg2[8];
    #pragma unroll
    for (int c = 0; c < 8; c++) {
        int ch = tid + c * 256;
        int row = ch >> 4, k8 = (ch & 15) * 8;
        wreg2[c] = *(const short8*)(W2t + row * H + k8);
    }
    __syncthreads();

    f32x4 a1[2][4] = {};
    #pragma unroll
    for (int ks = 0; ks < 4; ks++) {
        int kb = ks * 32 + (lane >> 4) * 8;
        short8 af[2], bfr[4];
        #pragma unroll
        for (int mi = 0; mi < 2; mi++) {
            int r = wr * 32 + mi * 16 + (lane & 15);
            af[mi] = *(const short8*)((const char*)S + SWZ(r, r * 256 + kb * 2));
        }
        #pragma unroll
        for (int ni = 0; ni < 4; ni++) {
            int n = wc * 64 + ni * 16 + (lane & 15);
            bfr[ni] = *(const short8*)((const char*)Wb + SWZ(n, n * 256 + kb * 2));
        }
        #pragma unroll
        for (int mi = 0; mi < 2; mi++)
            #pragma unroll
            for (int ni = 0; ni < 4; ni++)
                a1[mi][ni] = __builtin_amdgcn_mfma_f32_16x16x32_bf16(
                    af[mi], bfr[ni], a1[mi][ni], 0, 0, 0);
    }
    __syncthreads();

    #pragma unroll
    for (int ni = 0; ni < 4; ni++) {
        int n = wc * 64 + ni * 16 + (lane & 15);
        float bb = b1[n];
        #pragma unroll
        for (int mi = 0; mi < 2; mi++) {
            int mrow = wr * 32 + mi * 16 + ((lane >> 4) << 2);
            #pragma unroll
            for (int r = 0; r < 4; r++) {
                int m = mrow + r;
                float tv = fmaxf(a1[mi][ni][r] + bb, 0.f);
                *(ushort*)((char*)S + SWZ(m, m * 256 + n * 2)) = f2bfu(tv);
            }
        }
    }
    #pragma unroll
    for (int c = 0; c < 8; c++) {
        int ch = tid + c * 256;
        int row = ch >> 4, k8 = (ch & 15) * 8;
        *(short8*)((char*)Wb + SWZ(row, row * 256 + k8 * 2)) = wreg2[c];
    }
    __syncthreads();

    f32x4 a2[4][2] = {};
    #pragma unroll
    for (int ks = 0; ks < 4; ks++) {
        int kb = ks * 32 + (lane >> 4) * 8;
        short8 af[4], bfr[2];
        #pragma unroll
        for (int mi = 0; mi < 4; mi++) {
            int n2 = wr * 64 + mi * 16 + (lane & 15);
            af[mi] = *(const short8*)((const char*)Wb + SWZ(n2, n2 * 256 + kb * 2));
        }
        #pragma unroll
        for (int ni = 0; ni < 2; ni++) {
            int m = wc * 32 + ni * 16 + (lane & 15);
            bfr[ni] = *(const short8*)((const char*)S + SWZ(m, m * 256 + kb * 2));
        }
        #pragma unroll
        for (int mi = 0; mi < 4; mi++)
            #pragma unroll
            for (int ni = 0; ni < 2; ni++)
                a2[mi][ni] = __builtin_amdgcn_mfma_f32_16x16x32_bf16(
                    af[mi], bfr[ni], a2[mi][ni], 0, 0, 0);
    }

    if (!do_ln) {
        #pragma unroll
        for (int ni = 0; ni < 2; ni++) {
            int node = m0 + wc * 32 + ni * 16 + (lane & 15);
            if (node >= N_NODES) continue;
            #pragma unroll
            for (int mi = 0; mi < 4; mi++) {
                int n2b = wr * 64 + mi * 16 + ((lane >> 4) << 2);
                ulong xr = *(const ulong*)(xb + (size_t)node * H + n2b);
                const ushort* xp = (const ushort*)&xr;
                float4 bb = *(const float4*)(b2 + n2b);
                ushort us[4];
                us[0] = f2bfu(a2[mi][ni][0] + bb.x + bfu2f(xp[0]));
                us[1] = f2bfu(a2[mi][ni][1] + bb.y + bfu2f(xp[1]));
                us[2] = f2bfu(a2[mi][ni][2] + bb.z + bfu2f(xp[2]));
                us[3] = f2bfu(a2[mi][ni][3] + bb.w + bfu2f(xp[3]));
                *(ulong*)(xb + (size_t)node * H + n2b) = *(ulong*)us;
            }
        }
    } else {
        // last layer: keep fp32 pre-LN value in LDS (reuse Wb) and LayerNorm
        float* F = (float*)Wb;
        __syncthreads();
        #pragma unroll
        for (int ni = 0; ni < 2; ni++) {
            int nl = wc * 32 + ni * 16 + (lane & 15);   // 0..63
            int node = m0 + nl;
            #pragma unroll
            for (int mi = 0; mi < 4; mi++) {
                int n2b = wr * 64 + mi * 16 + ((lane >> 4) << 2);
                float4 o = {0.f, 0.f, 0.f, 0.f};
                if (node < N_NODES) {
                    ulong xr = *(const ulong*)(xb + (size_t)node * H + n2b);
                    const ushort* xp = (const ushort*)&xr;
                    float4 bb = *(const float4*)(b2 + n2b);
                    o.x = a2[mi][ni][0] + bb.x + bfu2f(xp[0]);
                    o.y = a2[mi][ni][1] + bb.y + bfu2f(xp[1]);
                    o.z = a2[mi][ni][2] + bb.z + bfu2f(xp[2]);
                    o.w = a2[mi][ni][3] + bb.w + bfu2f(xp[3]);
                }
                *(float4*)((char*)F + SWZ(nl, nl * 512 + n2b * 4)) = o;
            }
        }
        __syncthreads();
        float2 gm = ((const float2*)gamma)[lane];
        float2 bt = ((const float2*)beta)[lane];
        for (int i = 0; i < 16; i++) {
            int row = wid * 16 + i;
            int node = m0 + row;
            if (node >= N_NODES) break;   // wave-uniform
            float2 v = *(float2*)((char*)F + SWZ(row, row * 512 + lane * 8));
            float s = v.x + v.y;
            #pragma unroll
            for (int d = 1; d < 64; d <<= 1) s += __shfl_xor(s, d);
            float mu = s * (1.f / 128.f);
            float dx = v.x - mu, dy = v.y - mu;
            float q = dx * dx + dy * dy;
            #pragma unroll
            for (int d = 1; d < 64; d <<= 1) q += __shfl_xor(q, d);
            float inv = rsqrtf(q * (1.f / 128.f) + LN_EPS);
            float2 o2;
            o2.x = gm.x * dx * inv + bt.x;
            o2.y = gm.y * dy * inv + bt.y;
            ((float2*)(out + (size_t)node * H))[lane] = o2;
        }
    }
}

// ---------------- launcher ----------------

extern "C" void kernel_launch(void* const* d_in, const int* in_sizes, int n_in,
                              void* d_out, int out_size, void* d_ws, size_t ws_size,
                              hipStream_t stream) {
    const float* pep    = (const float*)d_in[0];
    const float* proj_W = (const float*)d_in[1];
    const float* proj_b = (const float*)d_in[2];
    const float* emb    = (const float*)d_in[3];
    const float* cW1    = (const float*)d_in[4];
    const float* cb1    = (const float*)d_in[5];
    const float* cW2    = (const float*)d_in[6];
    const float* cb2    = (const float*)d_in[7];
    const float* gamma  = (const float*)d_in[8];
    const float* beta   = (const float*)d_in[9];
    const int*   eidx   = (const int*)d_in[10];
    const int*   attr   = (const int*)d_in[11];
    const int* src = eidx;
    const int* dst = eidx + N_EDGES;

    char* w = (char*)d_ws;
    ushort* xb     = (ushort*)w;            w += (size_t)N_NODES * H * 2;
    ushort* aggb   = (ushort*)w;            w += (size_t)N_NODES * H * 2;
    short*  Wt     = (short*)w;             w += 128 * 512 * 2;
    short*  W1t    = (short*)w;             w += 3 * 128 * 128 * 2;
    short*  W2t    = (short*)w;             w += 3 * 128 * 128 * 2;
    ushort* embb   = (ushort*)w;            w += 100 * 128 * 2;
    int*    offs   = (int*)w;               w += (N_NODES + 16) * 4;
    int*    bcnt_part = (int*)w;            w += (size_t)BIN_BLOCKS * SCAN_B * 4;
    int*    bbase  = (int*)w;               w += 260 * 4;
    int*    bcur   = (int*)w;               w += 256 * 4;
    int*    epack  = (int*)w;               w += (size_t)N_EDGES * 4;
    int*    tmp_ep = (int*)w;               w += (size_t)N_EDGES * 4;
    ushort* tmp_dst = (ushort*)w;           w += (size_t)N_EDGES * 2;

    float* out = (float*)d_out;

    prep_w_k<<<256, 256, 0, stream>>>(proj_W, cW1, cW2, emb, dst,
                                      Wt, W1t, W2t, embb, bcnt_part);
    scanb_k<<<1, 256, 0, stream>>>(bcnt_part, bbase, bcur);
    binpass_k<<<BIN_BLOCKS, 256, 0, stream>>>(src, dst, attr, bcnt_part, bcur,
                                              tmp_ep, tmp_dst);
    finepass_k<<<SCAN_B, 256, 0, stream>>>(tmp_ep, tmp_dst, bbase, offs, epack);

    proj_k<<<(N_NODES + 255) / 256, 512, 0, stream>>>(pep, Wt, proj_b, xb);

    for (int l = 0; l < N_LAYERS; l++) {
        gather_k<<<(N_NODES * 64 + 255) / 256, 256, 0, stream>>>(
            xb, offs, epack, embb, aggb);
        mlp_k<<<(N_NODES + MLP_ROWS - 1) / MLP_ROWS, 256, 0, stream>>>(
            xb, aggb,
            W1t + (size_t)l * H * H, cb1 + (size_t)l * H,
            W2t + (size_t)l * H * H, cb2 + (size_t)l * H,
            gamma, beta, out,
            (l == N_LAYERS - 1) ? 1 : 0);
    }
}

// Round 15
// 252.510 us; speedup vs baseline: 1.0516x; 1.0119x over previous
//
#include <hip/hip_runtime.h>
#include <hip/hip_bf16.h>

#define N_NODES 50000
#define N_EDGES 800000
#define H 128
#define IN_DIM 512
#define N_LAYERS 3
#define LN_EPS 1e-5f
#define SCAN_B ((N_NODES + 255) / 256)   // 196 buckets of 256 nodes
#define BIN_CH 8192
#define BIN_BLOCKS ((N_EDGES + BIN_CH - 1) / BIN_CH)   // 98

typedef __attribute__((ext_vector_type(4))) float f32x4;
typedef __attribute__((ext_vector_type(8))) short short8;

__device__ inline ushort f2bfu(float f) {
    __hip_bfloat16 h = __float2bfloat16(f);
    return __builtin_bit_cast(ushort, h);
}
__device__ inline float bfu2f(ushort u) {
    uint v = ((uint)u) << 16;
    return __builtin_bit_cast(float, v);
}
__device__ inline float lobf(uint u) { return __builtin_bit_cast(float, u << 16); }
__device__ inline float hibf(uint u) { return __builtin_bit_cast(float, u & 0xffff0000u); }

// XOR swizzle: flip bits 4-6 of byte address with row&7 (bijective within a row)
#define SWZ(row, byte) ((byte) ^ (((row) & 7) << 4))

__device__ inline short8 cvt8(float4 a, float4 b) {
    short8 v;
    v[0] = (short)f2bfu(a.x); v[1] = (short)f2bfu(a.y);
    v[2] = (short)f2bfu(a.z); v[3] = (short)f2bfu(a.w);
    v[4] = (short)f2bfu(b.x); v[5] = (short)f2bfu(b.y);
    v[6] = (short)f2bfu(b.z); v[7] = (short)f2bfu(b.w);
    return v;
}

// ---------------- weight prep + per-block bucket partial counts ----------------

__global__ __launch_bounds__(256) void prep_w_k(const float* __restrict__ pW,
                                                const float* __restrict__ W1,
                                                const float* __restrict__ W2,
                                                const float* __restrict__ emb,
                                                const int* __restrict__ dst,
                                                short* __restrict__ Wt,
                                                short* __restrict__ W1t,
                                                short* __restrict__ W2t,
                                                ushort* __restrict__ embb,
                                                int* __restrict__ bcnt_part) {
    __shared__ int cnt[SCAN_B];
    int tid = threadIdx.x, bid = blockIdx.x;
    int i = bid * 256 + tid;
    if (i < 128 * 512) {
        int n = i >> 9, k = i & 511;
        Wt[i] = (short)f2bfu(pW[k * 128 + n]);
    }
    if (i < 3 * 128 * 128) {
        int l = i >> 14, rem = i & 16383, n = rem >> 7, k = rem & 127;
        W1t[i] = (short)f2bfu(W1[l * 16384 + k * 128 + n]);
        W2t[i] = (short)f2bfu(W2[l * 16384 + k * 128 + n]);
    }
    if (i < 100 * 128) embb[i] = f2bfu(emb[i]);

    if (bid < BIN_BLOCKS) {
        if (tid < SCAN_B) cnt[tid] = 0;
        __syncthreads();
        int e0 = bid * BIN_CH;
        #pragma unroll
        for (int k = 0; k < BIN_CH / 256; k++) {
            int e = e0 + k * 256 + tid;
            if (e < N_EDGES) atomicAdd(&cnt[dst[e] >> 8], 1);
        }
        __syncthreads();
        if (tid < SCAN_B) bcnt_part[bid * SCAN_B + tid] = cnt[tid];
    }
}

// reduce partials + scan 196 bucket counts -> bucket bases + cursors
__global__ __launch_bounds__(256) void scanb_k(const int* __restrict__ bcnt_part,
                                               int* __restrict__ bbase,
                                               int* __restrict__ bcur) {
    __shared__ int s[256];
    int t = threadIdx.x;
    int v = 0;
    if (t < SCAN_B)
        for (int b = 0; b < BIN_BLOCKS; b++) v += bcnt_part[b * SCAN_B + t];
    s[t] = v;
    __syncthreads();
    for (int d = 1; d < 256; d <<= 1) {
        int u = (t >= d) ? s[t - d] : 0;
        __syncthreads();
        s[t] += u;
        __syncthreads();
    }
    int exc = s[t] - v;   // for t >= SCAN_B this equals total == N_EDGES
    bbase[t] = exc;
    if (t < SCAN_B) bcur[t] = exc;
}

// bin pass: coarse bucket sort (dst>>8), LDS-staged bursts.
__global__ __launch_bounds__(256) void binpass_k(const int* __restrict__ src,
                                                 const int* __restrict__ dst,
                                                 const int* __restrict__ attr,
                                                 const int* __restrict__ bcnt_part,
                                                 int* __restrict__ bcur,
                                                 int* __restrict__ tmp_ep,
                                                 ushort* __restrict__ tmp_dst) {
    __shared__ int lofs[SCAN_B];
    __shared__ int gbase[SCAN_B];
    __shared__ int cnt2[SCAN_B];
    __shared__ int scan_s[256];
    __shared__ int stage_ep[BIN_CH];      // 32 KB
    __shared__ ushort stage_dst[BIN_CH];  // 16 KB
    int tid = threadIdx.x;
    int e0 = blockIdx.x * BIN_CH;

    int v = (tid < SCAN_B) ? bcnt_part[blockIdx.x * SCAN_B + tid] : 0;
    if (tid < SCAN_B) cnt2[tid] = 0;
    scan_s[tid] = v;
    __syncthreads();
    for (int d = 1; d < 256; d <<= 1) {
        int u = (tid >= d) ? scan_s[tid - d] : 0;
        __syncthreads();
        scan_s[tid] += u;
        __syncthreads();
    }
    if (tid < SCAN_B) lofs[tid] = scan_s[tid] - v;
    int total = scan_s[255];

    if (tid < SCAN_B && v > 0) gbase[tid] = atomicAdd(&bcur[tid], v);
    __syncthreads();

    #pragma unroll
    for (int k = 0; k < BIN_CH / 256; k++) {
        int e = e0 + k * 256 + tid;
        if (e < N_EDGES) {
            int d = dst[e];
            int b = d >> 8;
            int loc = lofs[b] + atomicAdd(&cnt2[b], 1);
            stage_ep[loc] = src[e] | (attr[e] << 16);
            stage_dst[loc] = (ushort)d;
        }
    }
    __syncthreads();

    for (int i = tid; i < total; i += 256) {
        ushort d = stage_dst[i];
        int b = d >> 8;
        int gp = gbase[b] + (i - lofs[b]);
        tmp_ep[gp] = stage_ep[i];
        tmp_dst[gp] = d;
    }
}

// fine pass: per-bucket node offsets + scatter to exact CSR slots
__global__ __launch_bounds__(256) void finepass_k(const int* __restrict__ tmp_ep,
                                                  const ushort* __restrict__ tmp_dst,
                                                  const int* __restrict__ bbase,
                                                  int* __restrict__ offs,
                                                  int* __restrict__ epack) {
    __shared__ int deg[256];
    __shared__ int cur[256];
    __shared__ int wsum[4];
    int tid = threadIdx.x;
    deg[tid] = 0;
    __syncthreads();
    int lo = bbase[blockIdx.x], hi = bbase[blockIdx.x + 1];
    for (int i = lo + tid; i < hi; i += 256)
        atomicAdd(&deg[tmp_dst[i] & 255], 1);
    __syncthreads();
    // exclusive scan of deg[256]
    int lane = tid & 63, w = tid >> 6;
    int v = deg[tid];
    int inc = v;
    #pragma unroll
    for (int d = 1; d < 64; d <<= 1) {
        int u = __shfl_up(inc, d);
        if (lane >= d) inc += u;
    }
    if (lane == 63) wsum[w] = inc;
    __syncthreads();
    int wo = 0;
    #pragma unroll
    for (int k = 0; k < 4; k++) if (k < w) wo += wsum[k];
    int exc = lo + wo + inc - v;
    int node = (blockIdx.x << 8) + tid;
    if (node < N_NODES) offs[node] = exc;
    if (node == N_NODES - 1) offs[N_NODES] = exc + v;
    cur[tid] = exc;
    __syncthreads();
    for (int i = lo + tid; i < hi; i += 256) {
        ushort d = tmp_dst[i];
        int ep = tmp_ep[i];
        int pos = atomicAdd(&cur[d & 255], 1);
        epack[pos] = ep;
    }
}

// ---------------- Projection: x = pep @ W + b  (W-resident, 4-deep prefetch; R12 form) ----------------

__global__ __launch_bounds__(512) void proj_k(const float* __restrict__ pep,
                                              const short* __restrict__ Wt,
                                              const float* __restrict__ b,
                                              ushort* __restrict__ xb) {
    __shared__ short SW[128 * 512];  // 128 KB; row = out-col n, stride 1024B, swizzled
    int tid = threadIdx.x, lane = tid & 63, wid = tid >> 6;

    #pragma unroll
    for (int c = 0; c < 16; c++) {
        int ch = tid + c * 512;
        int row = ch >> 6, kc = (ch & 63) * 16;
        short8 w = *(const short8*)((const char*)Wt + row * 1024 + kc);
        *(short8*)((char*)SW + SWZ(row, row * 1024 + kc)) = w;
    }
    __syncthreads();

    int m0 = blockIdx.x * 256 + wid * 32;

    const float* arow[2];
    #pragma unroll
    for (int mi = 0; mi < 2; mi++) {
        int node = m0 + mi * 16 + (lane & 15);
        if (node > N_NODES - 1) node = N_NODES - 1;
        arow[mi] = pep + (size_t)node * IN_DIM + ((lane >> 4) << 3);
    }

    f32x4 acc[2][8] = {};
    float4 A[4][2][2];   // 4-deep circular prefetch
    #pragma unroll
    for (int d = 0; d < 4; d++)
        #pragma unroll
        for (int mi = 0; mi < 2; mi++) {
            A[d][mi][0] = *(const float4*)(arow[mi] + d * 32);
            A[d][mi][1] = *(const float4*)(arow[mi] + d * 32 + 4);
        }

    #pragma unroll
    for (int ks = 0; ks < 16; ks++) {
        int d = ks & 3;
        short8 af0 = cvt8(A[d][0][0], A[d][0][1]);
        short8 af1 = cvt8(A[d][1][0], A[d][1][1]);
        if (ks + 4 < 16) {
            #pragma unroll
            for (int mi = 0; mi < 2; mi++) {
                A[d][mi][0] = *(const float4*)(arow[mi] + (ks + 4) * 32);
                A[d][mi][1] = *(const float4*)(arow[mi] + (ks + 4) * 32 + 4);
            }
        }
        int kb2 = (ks * 32 + ((lane >> 4) << 3)) * 2;
        #pragma unroll
        for (int ni = 0; ni < 8; ni++) {
            int n = ni * 16 + (lane & 15);
            short8 bf = *(const short8*)((const char*)SW + SWZ(n, n * 1024 + kb2));
            acc[0][ni] = __builtin_amdgcn_mfma_f32_16x16x32_bf16(af0, bf, acc[0][ni], 0, 0, 0);
            acc[1][ni] = __builtin_amdgcn_mfma_f32_16x16x32_bf16(af1, bf, acc[1][ni], 0, 0, 0);
        }
    }

    #pragma unroll
    for (int ni = 0; ni < 8; ni++) {
        int col = ni * 16 + (lane & 15);
        float bb = b[col];
        #pragma unroll
        for (int mi = 0; mi < 2; mi++) {
            int rowb = m0 + mi * 16 + ((lane >> 4) << 2);
            #pragma unroll
            for (int r = 0; r < 4; r++) {
                int node = rowb + r;
                if (node < N_NODES)
                    xb[(size_t)node * H + col] = f2bfu(acc[mi][ni][r] + bb);
            }
        }
    }
}

// ---------------- Edge gather (bf16 x + bf16 emb, 16-deep ILP) ----------------

__global__ __launch_bounds__(256) void gather_k(const ushort* __restrict__ xb,
                                                const int* __restrict__ offs,
                                                const int* __restrict__ epack,
                                                const ushort* __restrict__ embb,
                                                ushort* __restrict__ aggb) {
    int node = (blockIdx.x * 256 + threadIdx.x) >> 6;
    int lane = threadIdx.x & 63;
    if (node >= N_NODES) return;
    int beg = offs[node], end = offs[node + 1];
    float ax = 0.f, ay = 0.f;
    for (int base = beg; base < end; base += 64) {
        int myp = (base + lane < end) ? epack[base + lane] : 0;
        int cnt = min(64, end - base);
        int j = 0;
        // 16 outstanding edge-pairs (32 loads in flight) to cover L2 latency
        for (; j + 16 <= cnt; j += 16) {
            uint xv[16], ev[16];
            #pragma unroll
            for (int q = 0; q < 16; q++) {
                int p = __shfl(myp, j + q);
                xv[q] = *(const uint*)(xb + (size_t)(p & 0xffff) * H + lane * 2);
                ev[q] = *(const uint*)(embb + (size_t)(p >> 16) * H + lane * 2);
            }
            #pragma unroll
            for (int q = 0; q < 16; q++) {
                ax += fmaxf(lobf(xv[q]) + lobf(ev[q]), 0.f);
                ay += fmaxf(hibf(xv[q]) + hibf(ev[q]), 0.f);
            }
        }
        for (; j + 4 <= cnt; j += 4) {
            uint xv[4], ev[4];
            #pragma unroll
            for (int q = 0; q < 4; q++) {
                int p = __shfl(myp, j + q);
                xv[q] = *(const uint*)(xb + (size_t)(p & 0xffff) * H + lane * 2);
                ev[q] = *(const uint*)(embb + (size_t)(p >> 16) * H + lane * 2);
            }
            #pragma unroll
            for (int q = 0; q < 4; q++) {
                ax += fmaxf(lobf(xv[q]) + lobf(ev[q]), 0.f);
                ay += fmaxf(hibf(xv[q]) + hibf(ev[q]), 0.f);
            }
        }
        for (; j < cnt; j++) {
            int p = __shfl(myp, j);
            uint xv = *(const uint*)(xb + (size_t)(p & 0xffff) * H + lane * 2);
            uint evv = *(const uint*)(embb + (size_t)(p >> 16) * H + lane * 2);
            ax += fmaxf(lobf(xv) + lobf(evv), 0.f);
            ay += fmaxf(hibf(xv) + hibf(evv), 0.f);
        }
    }
    uint packed = (uint)f2bfu(ax) | ((uint)f2bfu(ay) << 16);
    *(uint*)(aggb + (size_t)node * H + lane * 2) = packed;
}

// ---------------- Fused MLP + residual (MFMA bf16, 64-row tiles); optional fused LN ----

#define MLP_ROWS 64
__global__ __launch_bounds__(256) void mlp_k(ushort* __restrict__ xb,
                                             const ushort* __restrict__ aggb,
                                             const short* __restrict__ W1t,
                                             const float* __restrict__ b1,
                                             const short* __restrict__ W2t,
                                             const float* __restrict__ b2,
                                             const float* __restrict__ gamma,
                                             const float* __restrict__ beta,
                                             float* __restrict__ out,
                                             int do_ln) {
    __shared__ short S[MLP_ROWS * 128];  // 16 KB
    __shared__ short Wb[128 * 128];      // 32 KB (reused as fp32 [64][128] for LN)
    int tid = threadIdx.x, lane = tid & 63, wid = tid >> 6;
    int wr = wid >> 1, wc = wid & 1;
    int m0 = blockIdx.x * MLP_ROWS;

    // stage h = bf16(x_bf16 + agg_bf16)
    #pragma unroll
    for (int c = 0; c < 4; c++) {
        int ch = tid + c * 256;
        int row = ch >> 4, k8 = (ch & 15) * 8;
        int node = m0 + row;
        short8 hv;
        if (node < N_NODES) {
            short8 xv = *(const short8*)(xb + (size_t)node * H + k8);
            short8 ag = *(const short8*)(aggb + (size_t)node * H + k8);
            #pragma unroll
            for (int q = 0; q < 8; q++)
                hv[q] = (short)f2bfu(bfu2f((ushort)xv[q]) + bfu2f((ushort)ag[q]));
        } else {
            hv = (short8)0;
        }
        *(short8*)((char*)S + SWZ(row, row * 256 + k8 * 2)) = hv;
    }
    #pragma unroll
    for (int c = 0; c < 8; c++) {
        int ch = tid + c * 256;
        int row = ch >> 4, k8 = (ch & 15) * 8;
        short8 w = *(const short8*)(W1t + row * H + k8);
        *(short8*)((char*)Wb + SWZ(row, row * 256 + k8 * 2)) = w;
    }
    short8 wreg2[8];
    #pragma unroll
    for (int c = 0; c < 8; c++) {
        int ch = tid + c * 256;
        int row = ch >> 4, k8 = (ch & 15) * 8;
        wreg2[c] = *(const short8*)(W2t + row * H + k8);
    }
    __syncthreads();

    f32x4 a1[2][4] = {};
    #pragma unroll
    for (int ks = 0; ks < 4; ks++) {
        int kb = ks * 32 + (lane >> 4) * 8;
        short8 af[2], bfr[4];
        #pragma unroll
        for (int mi = 0; mi < 2; mi++) {
            int r = wr * 32 + mi * 16 + (lane & 15);
            af[mi] = *(const short8*)((const char*)S + SWZ(r, r * 256 + kb * 2));
        }
        #pragma unroll
        for (int ni = 0; ni < 4; ni++) {
            int n = wc * 64 + ni * 16 + (lane & 15);
            bfr[ni] = *(const short8*)((const char*)Wb + SWZ(n, n * 256 + kb * 2));
        }
        #pragma unroll
        for (int mi = 0; mi < 2; mi++)
            #pragma unroll
            for (int ni = 0; ni < 4; ni++)
                a1[mi][ni] = __builtin_amdgcn_mfma_f32_16x16x32_bf16(
                    af[mi], bfr[ni], a1[mi][ni], 0, 0, 0);
    }
    __syncthreads();

    #pragma unroll
    for (int ni = 0; ni < 4; ni++) {
        int n = wc * 64 + ni * 16 + (lane & 15);
        float bb = b1[n];
        #pragma unroll
        for (int mi = 0; mi < 2; mi++) {
            int mrow = wr * 32 + mi * 16 + ((lane >> 4) << 2);
            #pragma unroll
            for (int r = 0; r < 4; r++) {
                int m = mrow + r;
                float tv = fmaxf(a1[mi][ni][r] + bb, 0.f);
                *(ushort*)((char*)S + SWZ(m, m * 256 + n * 2)) = f2bfu(tv);
            }
        }
    }
    #pragma unroll
    for (int c = 0; c < 8; c++) {
        int ch = tid + c * 256;
        int row = ch >> 4, k8 = (ch & 15) * 8;
        *(short8*)((char*)Wb + SWZ(row, row * 256 + k8 * 2)) = wreg2[c];
    }
    __syncthreads();

    f32x4 a2[4][2] = {};
    #pragma unroll
    for (int ks = 0; ks < 4; ks++) {
        int kb = ks * 32 + (lane >> 4) * 8;
        short8 af[4], bfr[2];
        #pragma unroll
        for (int mi = 0; mi < 4; mi++) {
            int n2 = wr * 64 + mi * 16 + (lane & 15);
            af[mi] = *(const short8*)((const char*)Wb + SWZ(n2, n2 * 256 + kb * 2));
        }
        #pragma unroll
        for (int ni = 0; ni < 2; ni++) {
            int m = wc * 32 + ni * 16 + (lane & 15);
            bfr[ni] = *(const short8*)((const char*)S + SWZ(m, m * 256 + kb * 2));
        }
        #pragma unroll
        for (int mi = 0; mi < 4; mi++)
            #pragma unroll
            for (int ni = 0; ni < 2; ni++)
                a2[mi][ni] = __builtin_amdgcn_mfma_f32_16x16x32_bf16(
                    af[mi], bfr[ni], a2[mi][ni], 0, 0, 0);
    }

    if (!do_ln) {
        #pragma unroll
        for (int ni = 0; ni < 2; ni++) {
            int node = m0 + wc * 32 + ni * 16 + (lane & 15);
            if (node >= N_NODES) continue;
            #pragma unroll
            for (int mi = 0; mi < 4; mi++) {
                int n2b = wr * 64 + mi * 16 + ((lane >> 4) << 2);
                ulong xr = *(const ulong*)(xb + (size_t)node * H + n2b);
                const ushort* xp = (const ushort*)&xr;
                float4 bb = *(const float4*)(b2 + n2b);
                ushort us[4];
                us[0] = f2bfu(a2[mi][ni][0] + bb.x + bfu2f(xp[0]));
                us[1] = f2bfu(a2[mi][ni][1] + bb.y + bfu2f(xp[1]));
                us[2] = f2bfu(a2[mi][ni][2] + bb.z + bfu2f(xp[2]));
                us[3] = f2bfu(a2[mi][ni][3] + bb.w + bfu2f(xp[3]));
                *(ulong*)(xb + (size_t)node * H + n2b) = *(ulong*)us;
            }
        }
    } else {
        // last layer: keep fp32 pre-LN value in LDS (reuse Wb) and LayerNorm
        float* F = (float*)Wb;
        __syncthreads();
        #pragma unroll
        for (int ni = 0; ni < 2; ni++) {
            int nl = wc * 32 + ni * 16 + (lane & 15);   // 0..63
            int node = m0 + nl;
            #pragma unroll
            for (int mi = 0; mi < 4; mi++) {
                int n2b = wr * 64 + mi * 16 + ((lane >> 4) << 2);
                float4 o = {0.f, 0.f, 0.f, 0.f};
                if (node < N_NODES) {
                    ulong xr = *(const ulong*)(xb + (size_t)node * H + n2b);
                    const ushort* xp = (const ushort*)&xr;
                    float4 bb = *(const float4*)(b2 + n2b);
                    o.x = a2[mi][ni][0] + bb.x + bfu2f(xp[0]);
                    o.y = a2[mi][ni][1] + bb.y + bfu2f(xp[1]);
                    o.z = a2[mi][ni][2] + bb.z + bfu2f(xp[2]);
                    o.w = a2[mi][ni][3] + bb.w + bfu2f(xp[3]);
                }
                *(float4*)((char*)F + SWZ(nl, nl * 512 + n2b * 4)) = o;
            }
        }
        __syncthreads();
        float2 gm = ((const float2*)gamma)[lane];
        float2 bt = ((const float2*)beta)[lane];
        for (int i = 0; i < 16; i++) {
            int row = wid * 16 + i;
            int node = m0 + row;
            if (node >= N_NODES) break;   // wave-uniform
            float2 v = *(float2*)((char*)F + SWZ(row, row * 512 + lane * 8));
            float s = v.x + v.y;
            #pragma unroll
            for (int d = 1; d < 64; d <<= 1) s += __shfl_xor(s, d);
            float mu = s * (1.f / 128.f);
            float dx = v.x - mu, dy = v.y - mu;
            float q = dx * dx + dy * dy;
            #pragma unroll
            for (int d = 1; d < 64; d <<= 1) q += __shfl_xor(q, d);
            float inv = rsqrtf(q * (1.f / 128.f) + LN_EPS);
            float2 o2;
            o2.x = gm.x * dx * inv + bt.x;
            o2.y = gm.y * dy * inv + bt.y;
            ((float2*)(out + (size_t)node * H))[lane] = o2;
        }
    }
}

// ---------------- launcher ----------------

extern "C" void kernel_launch(void* const* d_in, const int* in_sizes, int n_in,
                              void* d_out, int out_size, void* d_ws, size_t ws_size,
                              hipStream_t stream) {
    const float* pep    = (const float*)d_in[0];
    const float* proj_W = (const float*)d_in[1];
    const float* proj_b = (const float*)d_in[2];
    const float* emb    = (const float*)d_in[3];
    const float* cW1    = (const float*)d_in[4];
    const float* cb1    = (const float*)d_in[5];
    const float* cW2    = (const float*)d_in[6];
    const float* cb2    = (const float*)d_in[7];
    const float* gamma  = (const float*)d_in[8];
    const float* beta   = (const float*)d_in[9];
    const int*   eidx   = (const int*)d_in[10];
    const int*   attr   = (const int*)d_in[11];
    const int* src = eidx;
    const int* dst = eidx + N_EDGES;

    char* w = (char*)d_ws;
    ushort* xb     = (ushort*)w;            w += (size_t)N_NODES * H * 2;
    ushort* aggb   = (ushort*)w;            w += (size_t)N_NODES * H * 2;
    short*  Wt     = (short*)w;             w += 128 * 512 * 2;
    short*  W1t    = (short*)w;             w += 3 * 128 * 128 * 2;
    short*  W2t    = (short*)w;             w += 3 * 128 * 128 * 2;
    ushort* embb   = (ushort*)w;            w += 100 * 128 * 2;
    int*    offs   = (int*)w;               w += (N_NODES + 16) * 4;
    int*    bcnt_part = (int*)w;            w += (size_t)BIN_BLOCKS * SCAN_B * 4;
    int*    bbase  = (int*)w;               w += 260 * 4;
    int*    bcur   = (int*)w;               w += 256 * 4;
    int*    epack  = (int*)w;               w += (size_t)N_EDGES * 4;
    int*    tmp_ep = (int*)w;               w += (size_t)N_EDGES * 4;
    ushort* tmp_dst = (ushort*)w;           w += (size_t)N_EDGES * 2;

    float* out = (float*)d_out;

    prep_w_k<<<256, 256, 0, stream>>>(proj_W, cW1, cW2, emb, dst,
                                      Wt, W1t, W2t, embb, bcnt_part);
    scanb_k<<<1, 256, 0, stream>>>(bcnt_part, bbase, bcur);
    binpass_k<<<BIN_BLOCKS, 256, 0, stream>>>(src, dst, attr, bcnt_part, bcur,
                                              tmp_ep, tmp_dst);
    finepass_k<<<SCAN_B, 256, 0, stream>>>(tmp_ep, tmp_dst, bbase, offs, epack);

    proj_k<<<(N_NODES + 255) / 256, 512, 0, stream>>>(pep, Wt, proj_b, xb);

    for (int l = 0; l < N_LAYERS; l++) {
        gather_k<<<(N_NODES * 64 + 255) / 256, 256, 0, stream>>>(
            xb, offs, epack, embb, aggb);
        mlp_k<<<(N_NODES + MLP_ROWS - 1) / MLP_ROWS, 256, 0, stream>>>(
            xb, aggb,
            W1t + (size_t)l * H * H, cb1 + (size_t)l * H,
            W2t + (size_t)l * H * H, cb2 + (size_t)l * H,
            gamma, beta, out,
            (l == N_LAYERS - 1) ? 1 : 0);
    }
}